// Round 2
// baseline (527.306 us; speedup 1.0000x reference)
//
#include <hip/hip_runtime.h>
#include <hip/hip_bf16.h>
#include <cstdint>

// ---------------------------------------------------------------------------
// 3-layer GCN on MI355X — bf16 feature pipeline, f32 accumulate.
//   prep: x->bf16, W*->bf16 transposed (Wt[n][k]); CSR build (count/scan/fill)
//   R  = bf16( xb @ Wr + br )                     (MFMA GEMM)
//   A0 = bf16( xb @ W0 );  H0 = bf16(relu(S A0 + b0) + R)
//   A1 = bf16( H0 @ W1 );  H1 = bf16(relu(S A1 + b1))
//   A2 = bf16( H1 @ W2 );  out_f32 = relu(S A2 + b2)
// S = D^-1/2 (A+I) D^-1/2 gather-style, no float atomics; self-loop
// analytic (dinv^2 * h[node]).
//
// R5: bf16 + MFMA. R6: 2 nodes/wave. R8/R9: 4 nodes/wave + 8-padded CSR.
// R10: k_count was 67us at 0.5% VALU / 11% HBM with 56 MB WRITE_SIZE
// (~32 B/atomic of line-migration writeback) -> device-scope atomics execute
// at the memory-side coherence point. Fix: 8 per-XCD replica count planes
// (replica = real XCC_ID) + workgroup-scope atomicAdd so the RMW stays in
// the local TCC. pos packs (rank<<3)|replica; scan1 builds per-replica bases
// in-place + true degree tot[]; fill slot = rowstart + base[r][d] + rank.
// R11 (this): R10 bench died with a container-level failure (no counters).
// Only plausible kernel-side culprit was the raw `s_getreg_b32 hwreg(20,0,4)`
// inline asm -> replaced with __builtin_amdgcn_s_getreg(6164) (the verified
// HW_REG_XCC_ID path). Everything else identical to R10.
// ---------------------------------------------------------------------------

#define WS_ALIGN(x) (((x) + 255) & ~(size_t)255)

typedef __bf16 bf16x8 __attribute__((ext_vector_type(8)));
typedef float  floatx4 __attribute__((ext_vector_type(4)));

static __device__ __forceinline__ float bf_lo(unsigned u) {
  return __builtin_bit_cast(float, u << 16);
}
static __device__ __forceinline__ float bf_hi(unsigned u) {
  return __builtin_bit_cast(float, u & 0xffff0000u);
}
// f32 -> bf16 round-to-nearest-even (finite inputs only)
static __device__ __forceinline__ unsigned short f2bs(float f) {
  unsigned u = __builtin_bit_cast(unsigned, f);
  return (unsigned short)((u + 0x7fffu + ((u >> 16) & 1u)) >> 16);
}
static __device__ __forceinline__ unsigned pack2(float a, float b) {
  return (unsigned)f2bs(a) | ((unsigned)f2bs(b) << 16);
}

// ---------------- fused prep: zero cnt planes | x->bf16 | W->Wt bf16 -------
__global__ void k_prep(const float* __restrict__ x, unsigned* __restrict__ xb, int n4,
                       int* __restrict__ cnt8, int nz,
                       const float* __restrict__ W0, const float* __restrict__ W1,
                       const float* __restrict__ W2, const float* __restrict__ Wr,
                       unsigned short* __restrict__ Wt, int zb, int xbn) {
  int b = blockIdx.x;
  if (b < zb) {
    int i = b * 256 + threadIdx.x;
    if (i < nz) cnt8[i] = 0;
  } else if (b < zb + xbn) {
    int i = (b - zb) * 256 + threadIdx.x;
    if (i < n4) {
      float4 v = ((const float4*)x)[i];
      uint2 o;
      o.x = pack2(v.x, v.y);
      o.y = pack2(v.z, v.w);
      ((uint2*)xb)[i] = o;
    }
  } else {
    int wb = b - zb - xbn;            // 0..255
    int mat = wb >> 6, blk = wb & 63;
    const float* W = mat == 0 ? W0 : mat == 1 ? W1 : mat == 2 ? W2 : Wr;
    unsigned short* T = Wt + (size_t)mat * 16384;
    int i = blk * 256 + threadIdx.x;  // i = k*128 + nn, coalesced read
    int k = i >> 7, nn = i & 127;
    T[nn * 128 + k] = f2bs(W[i]);
  }
}

// In-degree count + per-edge slot, per-XCD replicated to keep the atomic RMW
// in the local TCC (workgroup scope => no cross-XCD coherence round trip).
// Replica purity is guaranteed by reading the hardware XCC_ID (workgroup ->
// one CU -> one XCD; value is workgroup-uniform), so this does NOT depend on
// the (undefined) blockIdx->XCD mapping. Atomics bypass L1 and execute in
// the XCD's L2, so the RMW is atomic across all workgroups of that XCD.
__global__ void k_count(const int* __restrict__ dst, int E,
                        int* __restrict__ cnt8, int* __restrict__ pos, int NP) {
  // SIMM16 = (size-1)<<11 | offset<<6 | id : size=4 bits, offset=0,
  // id=20 (HW_REG_XCC_ID) -> 3<<11 | 20 = 6164. [learn_hip m09]
  unsigned xcc = __builtin_amdgcn_s_getreg(6164);
  int r = xcc & 7;
  int e = blockIdx.x * blockDim.x + threadIdx.x;
  if (e < E) {
    int d = dst[e];
    int rank = __hip_atomic_fetch_add(&cnt8[(size_t)r * NP + d], 1,
                                      __ATOMIC_RELAXED, __HIP_MEMORY_SCOPE_WORKGROUP);
    pos[e] = (rank << 3) | r;
  }
}

// Block-wise exclusive scan over PADDED totals ((tot+7)&~7), 1024/block.
// Also: per-node exclusive prefix across the 8 replica planes (in-place,
// planes become per-replica bases), true degree -> tot[], dinv from tot.
__global__ __launch_bounds__(1024) void k_scan1(int* __restrict__ cnt8, int n, int NP,
                                                int* __restrict__ rs, int* __restrict__ bsum,
                                                float* __restrict__ dinv,
                                                int* __restrict__ tot) {
  __shared__ int tmp[1024];
  int tid = threadIdx.x;
  int i = blockIdx.x * 1024 + tid;
  int t = 0;
  if (i < n) {
    int run = 0;
#pragma unroll
    for (int r = 0; r < 8; r++) {
      size_t idx = (size_t)r * NP + i;
      int c = cnt8[idx];
      cnt8[idx] = run;                // exclusive base for this replica
      run += c;
    }
    t = run;
    tot[i] = t;
    dinv[i] = rsqrtf((float)(t + 1)); // +1 = self-loop; always > 0
  }
  int vp = (t + 7) & ~7;              // 8-padded segment size
  tmp[tid] = vp;
  __syncthreads();
  for (int off = 1; off < 1024; off <<= 1) {
    int tv = (tid >= off) ? tmp[tid - off] : 0;
    __syncthreads();
    tmp[tid] += tv;
    __syncthreads();
  }
  if (i < n) rs[i] = tmp[tid] - vp;   // exclusive (block-local, padded)
  if (tid == 1023) bsum[blockIdx.x] = tmp[1023];
}

__global__ __launch_bounds__(128) void k_scan2(int* bsum, int nb) {
  __shared__ int tmp[128];
  int tid = threadIdx.x;
  int v = (tid < nb) ? bsum[tid] : 0;
  tmp[tid] = v;
  __syncthreads();
  for (int off = 1; off < 128; off <<= 1) {
    int t = (tid >= off) ? tmp[tid - off] : 0;
    __syncthreads();
    tmp[tid] += t;
    __syncthreads();
  }
  if (tid < nb) bsum[tid] = tmp[tid] - v;    // exclusive
}

// Atomic-free packed fill + pad writer. Threads [0,E): scatter one 8 B store
// per edge {src, bits(w)} to slot rs[d]+bsum+base[r][d]+rank. Threads
// [E, E+n): node pad slots [tot, (tot+7)&~7) get {0,0}.
__global__ void k_fill(const int* __restrict__ src, const int* __restrict__ dst, int E,
                       const int* __restrict__ rs, const int* __restrict__ bsum,
                       const int* __restrict__ pos, const int* __restrict__ cnt8,
                       const int* __restrict__ tot, int NP,
                       const float* __restrict__ dinv,
                       int2* __restrict__ epk, int n) {
  int e = blockIdx.x * blockDim.x + threadIdx.x;
  if (e < E) {
    int s = src[e], d = dst[e];
    int pr = pos[e];
    int idx = rs[d] + bsum[d >> 10] + cnt8[(size_t)(pr & 7) * NP + d] + (pr >> 3);
    int2 v;
    v.x = s;
    v.y = __float_as_int(dinv[s] * dinv[d]);
    epk[idx] = v;
  } else if (e - E < n) {
    int node = e - E;
    int c = tot[node];
    int cp = (c + 7) & ~7;
    int base = rs[node] + bsum[node >> 10];
    int2 z; z.x = 0; z.y = 0;
    for (int k = base + c; k < base + cp; k++) epk[k] = z;
  }
}

// ---------------- bf16 MFMA GEMM: Y[n,128] = bf16( Xb[n,128] @ W + bias ) ---
// Wt pre-transposed [n][k] bf16, staged in 32 KB LDS. Block = 256 thr =
// 4 waves; each wave computes a 16-row x 128-col strip with 32 MFMAs.
// Layouts (verified, learn_hip m89/m120): A[m=lane&15][k=quad*8+j],
// B[k=quad*8+j][n=lane&15], C/D col=lane&15 row=quad*4+reg.
__global__ __launch_bounds__(256, 2) void k_gemm_mfma(
    const unsigned short* __restrict__ Xb,
    const unsigned short* __restrict__ Wt,
    const float* __restrict__ bias,
    unsigned short* __restrict__ Y,
    int n) {
  __shared__ unsigned short sWt[128 * 128];
  {
    const uint4* s4 = (const uint4*)Wt;
    uint4* d4 = (uint4*)sWt;
    for (int i = threadIdx.x; i < 2048; i += 256) d4[i] = s4[i];
  }
  __syncthreads();

  const int lane = threadIdx.x & 63;
  const int wave = threadIdx.x >> 6;
  const int l15 = lane & 15;
  const int quad = lane >> 4;
  const int rbase = blockIdx.x * 64 + wave * 16;

  const bf16x8* sW8 = (const bf16x8*)sWt;
  bf16x8 b[8][4];
#pragma unroll
  for (int ct = 0; ct < 8; ct++)
#pragma unroll
    for (int kc = 0; kc < 4; kc++)
      b[ct][kc] = sW8[(ct * 16 + l15) * 16 + kc * 4 + quad];

  int row = rbase + l15;
  row = row < n ? row : n - 1;
  const bf16x8* X8 = (const bf16x8*)Xb;
  bf16x8 a[4];
#pragma unroll
  for (int kc = 0; kc < 4; kc++)
    a[kc] = X8[(size_t)row * 16 + kc * 4 + quad];

  floatx4 acc[8];
#pragma unroll
  for (int ct = 0; ct < 8; ct++) acc[ct] = (floatx4){0.f, 0.f, 0.f, 0.f};

#pragma unroll
  for (int kc = 0; kc < 4; kc++)
#pragma unroll
    for (int ct = 0; ct < 8; ct++)
      acc[ct] = __builtin_amdgcn_mfma_f32_16x16x32_bf16(a[kc], b[ct][kc], acc[ct], 0, 0, 0);

  const int orow = rbase + quad * 4;
#pragma unroll
  for (int ct = 0; ct < 8; ct++) {
    const int c = ct * 16 + l15;
    const float bv = bias ? bias[c] : 0.f;
#pragma unroll
    for (int r4 = 0; r4 < 4; r4++) {
      int r = orow + r4;
      if (r < n) Y[(size_t)r * 128 + c] = f2bs(acc[ct][r4] + bv);
    }
  }
}

// ---------------- aggregation ----------------
// FOUR nodes per wave: 16-lane quarter-waves each own a node; lane covers
// 8 bf16 cols as one uint4 (16 B). One gather instruction = 4 edges.
// CSR segments are 8-padded, so the MLP-8 batch needs NO predication and
// epk reads are 4x int4 (16 B aligned, quarter-uniform broadcast).
static __device__ __forceinline__ void fma8(float wgt, uint4 h, float* a) {
  a[0] = fmaf(wgt, bf_lo(h.x), a[0]);
  a[1] = fmaf(wgt, bf_hi(h.x), a[1]);
  a[2] = fmaf(wgt, bf_lo(h.y), a[2]);
  a[3] = fmaf(wgt, bf_hi(h.y), a[3]);
  a[4] = fmaf(wgt, bf_lo(h.z), a[4]);
  a[5] = fmaf(wgt, bf_hi(h.z), a[5]);
  a[6] = fmaf(wgt, bf_lo(h.w), a[6]);
  a[7] = fmaf(wgt, bf_hi(h.w), a[7]);
}

__global__ __launch_bounds__(256, 4) void k_agg(
    const uint4* __restrict__ H,         // bf16x8 per lane [n*16]
    const int* __restrict__ rs,
    const int* __restrict__ bsum,
    const int* __restrict__ tot,
    const int2* __restrict__ epk,
    const float* __restrict__ dinv,
    const float* __restrict__ bias,
    const uint4* __restrict__ resid,     // bf16x8 or null
    uint4* __restrict__ outb,            // bf16 out (layers 0,1) or null
    float4* __restrict__ outf,           // f32 out (layer 2) or null
    int n) {
  int node = blockIdx.x * 16 + (threadIdx.x >> 4);
  int l = threadIdx.x & 15;
  if (node >= n) return;

  float di = dinv[node];
  float ws = di * di;
  uint4 hv = H[(size_t)node * 16 + l];
  float a[8];
  a[0] = bf_lo(hv.x) * ws; a[1] = bf_hi(hv.x) * ws;
  a[2] = bf_lo(hv.y) * ws; a[3] = bf_hi(hv.y) * ws;
  a[4] = bf_lo(hv.z) * ws; a[5] = bf_hi(hv.z) * ws;
  a[6] = bf_lo(hv.w) * ws; a[7] = bf_hi(hv.w) * ws;

  int beg = rs[node] + bsum[node >> 10];
  int pdeg = (tot[node] + 7) & ~7;     // 8-padded degree
  const int4* epk4 = (const int4*)epk;

  for (int j = 0; j < pdeg; j += 8) {
    int b2 = (beg + j) >> 1;           // int4 index (beg is 8-aligned)
    int4 e0 = epk4[b2 + 0];
    int4 e1 = epk4[b2 + 1];
    int4 e2 = epk4[b2 + 2];
    int4 e3 = epk4[b2 + 3];
    uint4 h0 = H[(size_t)(unsigned)e0.x * 16 + l];
    uint4 h1 = H[(size_t)(unsigned)e0.z * 16 + l];
    uint4 h2 = H[(size_t)(unsigned)e1.x * 16 + l];
    uint4 h3 = H[(size_t)(unsigned)e1.z * 16 + l];
    uint4 h4 = H[(size_t)(unsigned)e2.x * 16 + l];
    uint4 h5 = H[(size_t)(unsigned)e2.z * 16 + l];
    uint4 h6 = H[(size_t)(unsigned)e3.x * 16 + l];
    uint4 h7 = H[(size_t)(unsigned)e3.z * 16 + l];
    fma8(__int_as_float(e0.y), h0, a);
    fma8(__int_as_float(e0.w), h1, a);
    fma8(__int_as_float(e1.y), h2, a);
    fma8(__int_as_float(e1.w), h3, a);
    fma8(__int_as_float(e2.y), h4, a);
    fma8(__int_as_float(e2.w), h5, a);
    fma8(__int_as_float(e3.y), h6, a);
    fma8(__int_as_float(e3.w), h7, a);
  }

  float4 bl = ((const float4*)bias)[l * 2];
  float4 bh = ((const float4*)bias)[l * 2 + 1];
  a[0] = fmaxf(a[0] + bl.x, 0.f); a[1] = fmaxf(a[1] + bl.y, 0.f);
  a[2] = fmaxf(a[2] + bl.z, 0.f); a[3] = fmaxf(a[3] + bl.w, 0.f);
  a[4] = fmaxf(a[4] + bh.x, 0.f); a[5] = fmaxf(a[5] + bh.y, 0.f);
  a[6] = fmaxf(a[6] + bh.z, 0.f); a[7] = fmaxf(a[7] + bh.w, 0.f);
  if (resid) {
    uint4 r = resid[(size_t)node * 16 + l];
    a[0] += bf_lo(r.x); a[1] += bf_hi(r.x);
    a[2] += bf_lo(r.y); a[3] += bf_hi(r.y);
    a[4] += bf_lo(r.z); a[5] += bf_hi(r.z);
    a[6] += bf_lo(r.w); a[7] += bf_hi(r.w);
  }
  if (outb) {
    uint4 o;
    o.x = pack2(a[0], a[1]); o.y = pack2(a[2], a[3]);
    o.z = pack2(a[4], a[5]); o.w = pack2(a[6], a[7]);
    outb[(size_t)node * 16 + l] = o;
  } else {
    float4 o0; o0.x = a[0]; o0.y = a[1]; o0.z = a[2]; o0.w = a[3];
    float4 o1; o1.x = a[4]; o1.y = a[5]; o1.z = a[6]; o1.w = a[7];
    outf[(size_t)node * 32 + l * 2] = o0;
    outf[(size_t)node * 32 + l * 2 + 1] = o1;
  }
}

extern "C" void kernel_launch(void* const* d_in, const int* in_sizes, int n_in,
                              void* d_out, int out_size, void* d_ws, size_t ws_size,
                              hipStream_t stream) {
  const float* x  = (const float*)d_in[0];
  const int* edges = (const int*)d_in[1];
  const float* W0 = (const float*)d_in[2];
  const float* b0 = (const float*)d_in[3];
  const float* W1 = (const float*)d_in[4];
  const float* b1 = (const float*)d_in[5];
  const float* W2 = (const float*)d_in[6];
  const float* b2 = (const float*)d_in[7];
  const float* Wr = (const float*)d_in[8];
  const float* br = (const float*)d_in[9];

  int N = in_sizes[0] / 128;
  int E = in_sizes[1] / 2;
  const int* src = edges;
  const int* dst = edges + E;

  char* ws = (char*)d_ws;
  size_t off = 0;
  auto alloc = [&](size_t bytes) -> void* {
    void* p = ws + off; off = WS_ALIGN(off + bytes); return p;
  };
  int*   tot    = (int*)  alloc((size_t)N * 4);     // true in-degree (pre-loop)
  float* dinv   = (float*)alloc((size_t)N * 4);
  int*   rs     = (int*)  alloc((size_t)(N + 1) * 4);
  int*   bsum   = (int*)  alloc(1024);
  int2*  epk    = (int2*) alloc(((size_t)E + 8 * (size_t)N) * 8);  // 8-padded CSR
  unsigned short* xb = (unsigned short*)alloc((size_t)N * 128 * 2);
  unsigned short* Wt = (unsigned short*)alloc((size_t)4 * 16384 * 2);
  unsigned short* A  = (unsigned short*)alloc((size_t)N * 128 * 2);
  unsigned short* Hb = (unsigned short*)alloc((size_t)N * 128 * 2);
  unsigned short* R  = (unsigned short*)alloc((size_t)N * 128 * 2);
  int* pos = (int*)A;   // pos[E] only lives between k_count and k_fill;
                        // A is first written after k_fill completes.
  // 8 per-XCD count planes (stride NP, 64B-multiple so no line straddles two
  // planes). Alias into Hb: dead until the first k_agg writes Hb (post-fill).
  int NP = (N + 15) & ~15;
  int* cnt8 = (int*)Hb;
  int nz = 8 * NP;
  (void)ws_size; (void)n_in; (void)out_size;

  int nb1 = (N + 1023) / 1024;   // 98 for N=100000 (must be <= 128)

  // ---- fused prep + CSR build ----
  int n4 = N * 128 / 4;
  int zb = (nz + 255) / 256;
  int xbn = (n4 + 255) / 256;
  k_prep <<<zb + xbn + 256, 256, 0, stream>>>(x, (unsigned*)xb, n4, cnt8, nz,
                                              W0, W1, W2, Wr, Wt, zb, xbn);
  k_count<<<(E + 255) / 256, 256, 0, stream>>>(dst, E, cnt8, pos, NP);
  k_scan1<<<nb1, 1024, 0, stream>>>(cnt8, N, NP, rs, bsum, dinv, tot);
  k_scan2<<<1, 128, 0, stream>>>(bsum, nb1);
  k_fill <<<(E + N + 255) / 256, 256, 0, stream>>>(src, dst, E, rs, bsum, pos,
                                                   cnt8, tot, NP, dinv, epk, N);

  // ---- GCN layers ----
  int gb = (N + 63) / 64;
  int ab = (N + 15) / 16;   // 16 nodes (quarter-waves) per 256-thread block

  unsigned short* Wt0 = Wt;
  unsigned short* Wt1 = Wt + 16384;
  unsigned short* Wt2 = Wt + 2 * 16384;
  unsigned short* Wtr = Wt + 3 * 16384;

  k_gemm_mfma<<<gb, 256, 0, stream>>>(xb, Wtr, br, R, N);       // residual
  k_gemm_mfma<<<gb, 256, 0, stream>>>(xb, Wt0, nullptr, A, N);
  k_agg<<<ab, 256, 0, stream>>>((const uint4*)A, rs, bsum, tot, epk, dinv, b0,
                                (const uint4*)R, (uint4*)Hb, nullptr, N);
  k_gemm_mfma<<<gb, 256, 0, stream>>>(Hb, Wt1, nullptr, A, N);
  k_agg<<<ab, 256, 0, stream>>>((const uint4*)A, rs, bsum, tot, epk, dinv, b1,
                                nullptr, (uint4*)R, nullptr, N);
  k_gemm_mfma<<<gb, 256, 0, stream>>>(R, Wt2, nullptr, A, N);
  k_agg<<<ab, 256, 0, stream>>>((const uint4*)A, rs, bsum, tot, epk, dinv, b2,
                                nullptr, nullptr, (float4*)d_out, N);
}

// Round 3
// 526.912 us; speedup vs baseline: 1.0007x; 1.0007x over previous
//
#include <hip/hip_runtime.h>
#include <hip/hip_bf16.h>
#include <cstdint>

// ---------------------------------------------------------------------------
// 3-layer GCN on MI355X — bf16 feature pipeline, f32 accumulate.
//   prep: x->bf16, W*->bf16 transposed (Wt[n][k]); CSR build (count/scan/fill)
//   R  = bf16( xb @ Wr + br )                     (MFMA GEMM)
//   A0 = bf16( xb @ W0 );  H0 = bf16(relu(S A0 + b0) + R)
//   A1 = bf16( H0 @ W1 );  H1 = bf16(relu(S A1 + b1))
//   A2 = bf16( H1 @ W2 );  out_f32 = relu(S A2 + b2)
// S = D^-1/2 (A+I) D^-1/2 gather-style, no float atomics; self-loop
// analytic (dinv^2 * h[node]).
//
// R5: bf16+MFMA. R6: 2 nodes/wave. R8/R9: 4 nodes/wave + 8-padded CSR.
// R10/R11: per-XCD replica k_count planes (workgroup-scope atomics).
// Post-mortem: total unchanged => k_count barely moved; atomics execute
// memory-side regardless of scope. Keep replicas, stop chasing count.
// R12 (this): k_agg = 3x65.5us, VALU 25%, 3.85TB/s L2-miss path, occ 60%
// => LATENCY-bound gather (only 8 rows in flight/wave). Fix: 16-padded CSR
// + 16 edges per iteration (8 int4 epk loads + 16 uint4 gathers in flight),
// consuming in load order. ~115 VGPR, 4 waves/SIMD; in-flight rows +68%.
// ---------------------------------------------------------------------------

#define WS_ALIGN(x) (((x) + 255) & ~(size_t)255)

typedef __bf16 bf16x8 __attribute__((ext_vector_type(8)));
typedef float  floatx4 __attribute__((ext_vector_type(4)));

static __device__ __forceinline__ float bf_lo(unsigned u) {
  return __builtin_bit_cast(float, u << 16);
}
static __device__ __forceinline__ float bf_hi(unsigned u) {
  return __builtin_bit_cast(float, u & 0xffff0000u);
}
// f32 -> bf16 round-to-nearest-even (finite inputs only)
static __device__ __forceinline__ unsigned short f2bs(float f) {
  unsigned u = __builtin_bit_cast(unsigned, f);
  return (unsigned short)((u + 0x7fffu + ((u >> 16) & 1u)) >> 16);
}
static __device__ __forceinline__ unsigned pack2(float a, float b) {
  return (unsigned)f2bs(a) | ((unsigned)f2bs(b) << 16);
}

// ---------------- fused prep: zero cnt planes | x->bf16 | W->Wt bf16 -------
__global__ void k_prep(const float* __restrict__ x, unsigned* __restrict__ xb, int n4,
                       int* __restrict__ cnt8, int nz,
                       const float* __restrict__ W0, const float* __restrict__ W1,
                       const float* __restrict__ W2, const float* __restrict__ Wr,
                       unsigned short* __restrict__ Wt, int zb, int xbn) {
  int b = blockIdx.x;
  if (b < zb) {
    int i = b * 256 + threadIdx.x;
    if (i < nz) cnt8[i] = 0;
  } else if (b < zb + xbn) {
    int i = (b - zb) * 256 + threadIdx.x;
    if (i < n4) {
      float4 v = ((const float4*)x)[i];
      uint2 o;
      o.x = pack2(v.x, v.y);
      o.y = pack2(v.z, v.w);
      ((uint2*)xb)[i] = o;
    }
  } else {
    int wb = b - zb - xbn;            // 0..255
    int mat = wb >> 6, blk = wb & 63;
    const float* W = mat == 0 ? W0 : mat == 1 ? W1 : mat == 2 ? W2 : Wr;
    unsigned short* T = Wt + (size_t)mat * 16384;
    int i = blk * 256 + threadIdx.x;  // i = k*128 + nn, coalesced read
    int k = i >> 7, nn = i & 127;
    T[nn * 128 + k] = f2bs(W[i]);
  }
}

// In-degree count + per-edge slot, per-XCD replicated (see R10 notes).
__global__ void k_count(const int* __restrict__ dst, int E,
                        int* __restrict__ cnt8, int* __restrict__ pos, int NP) {
  // SIMM16 = (size-1)<<11 | offset<<6 | id : size=4 bits, offset=0,
  // id=20 (HW_REG_XCC_ID) -> 3<<11 | 20 = 6164. [learn_hip m09]
  unsigned xcc = __builtin_amdgcn_s_getreg(6164);
  int r = xcc & 7;
  int e = blockIdx.x * blockDim.x + threadIdx.x;
  if (e < E) {
    int d = dst[e];
    int rank = __hip_atomic_fetch_add(&cnt8[(size_t)r * NP + d], 1,
                                      __ATOMIC_RELAXED, __HIP_MEMORY_SCOPE_WORKGROUP);
    pos[e] = (rank << 3) | r;
  }
}

// Block-wise exclusive scan over PADDED totals ((tot+15)&~15), 1024/block.
// Also: per-node exclusive prefix across the 8 replica planes (in-place,
// planes become per-replica bases), true degree -> tot[], dinv from tot.
__global__ __launch_bounds__(1024) void k_scan1(int* __restrict__ cnt8, int n, int NP,
                                                int* __restrict__ rs, int* __restrict__ bsum,
                                                float* __restrict__ dinv,
                                                int* __restrict__ tot) {
  __shared__ int tmp[1024];
  int tid = threadIdx.x;
  int i = blockIdx.x * 1024 + tid;
  int t = 0;
  if (i < n) {
    int run = 0;
#pragma unroll
    for (int r = 0; r < 8; r++) {
      size_t idx = (size_t)r * NP + i;
      int c = cnt8[idx];
      cnt8[idx] = run;                // exclusive base for this replica
      run += c;
    }
    t = run;
    tot[i] = t;
    dinv[i] = rsqrtf((float)(t + 1)); // +1 = self-loop; always > 0
  }
  int vp = (t + 15) & ~15;            // 16-padded segment size
  tmp[tid] = vp;
  __syncthreads();
  for (int off = 1; off < 1024; off <<= 1) {
    int tv = (tid >= off) ? tmp[tid - off] : 0;
    __syncthreads();
    tmp[tid] += tv;
    __syncthreads();
  }
  if (i < n) rs[i] = tmp[tid] - vp;   // exclusive (block-local, padded)
  if (tid == 1023) bsum[blockIdx.x] = tmp[1023];
}

__global__ __launch_bounds__(128) void k_scan2(int* bsum, int nb) {
  __shared__ int tmp[128];
  int tid = threadIdx.x;
  int v = (tid < nb) ? bsum[tid] : 0;
  tmp[tid] = v;
  __syncthreads();
  for (int off = 1; off < 128; off <<= 1) {
    int t = (tid >= off) ? tmp[tid - off] : 0;
    __syncthreads();
    tmp[tid] += t;
    __syncthreads();
  }
  if (tid < nb) bsum[tid] = tmp[tid] - v;    // exclusive
}

// Atomic-free packed fill + pad writer. Threads [0,E): scatter one 8 B store
// per edge {src, bits(w)} to slot rs[d]+bsum+base[r][d]+rank. Threads
// [E, E+n): node pad slots [tot, (tot+15)&~15) get {0,0} (gather of node 0
// with weight 0).
__global__ void k_fill(const int* __restrict__ src, const int* __restrict__ dst, int E,
                       const int* __restrict__ rs, const int* __restrict__ bsum,
                       const int* __restrict__ pos, const int* __restrict__ cnt8,
                       const int* __restrict__ tot, int NP,
                       const float* __restrict__ dinv,
                       int2* __restrict__ epk, int n) {
  int e = blockIdx.x * blockDim.x + threadIdx.x;
  if (e < E) {
    int s = src[e], d = dst[e];
    int pr = pos[e];
    int idx = rs[d] + bsum[d >> 10] + cnt8[(size_t)(pr & 7) * NP + d] + (pr >> 3);
    int2 v;
    v.x = s;
    v.y = __float_as_int(dinv[s] * dinv[d]);
    epk[idx] = v;
  } else if (e - E < n) {
    int node = e - E;
    int c = tot[node];
    int cp = (c + 15) & ~15;
    int base = rs[node] + bsum[node >> 10];
    int2 z; z.x = 0; z.y = 0;
    for (int k = base + c; k < base + cp; k++) epk[k] = z;
  }
}

// ---------------- bf16 MFMA GEMM: Y[n,128] = bf16( Xb[n,128] @ W + bias ) ---
// Wt pre-transposed [n][k] bf16, staged in 32 KB LDS. Block = 256 thr =
// 4 waves; each wave computes a 16-row x 128-col strip with 32 MFMAs.
// Layouts (verified, learn_hip m89/m120): A[m=lane&15][k=quad*8+j],
// B[k=quad*8+j][n=lane&15], C/D col=lane&15 row=quad*4+reg.
__global__ __launch_bounds__(256, 2) void k_gemm_mfma(
    const unsigned short* __restrict__ Xb,
    const unsigned short* __restrict__ Wt,
    const float* __restrict__ bias,
    unsigned short* __restrict__ Y,
    int n) {
  __shared__ unsigned short sWt[128 * 128];
  {
    const uint4* s4 = (const uint4*)Wt;
    uint4* d4 = (uint4*)sWt;
    for (int i = threadIdx.x; i < 2048; i += 256) d4[i] = s4[i];
  }
  __syncthreads();

  const int lane = threadIdx.x & 63;
  const int wave = threadIdx.x >> 6;
  const int l15 = lane & 15;
  const int quad = lane >> 4;
  const int rbase = blockIdx.x * 64 + wave * 16;

  const bf16x8* sW8 = (const bf16x8*)sWt;
  bf16x8 b[8][4];
#pragma unroll
  for (int ct = 0; ct < 8; ct++)
#pragma unroll
    for (int kc = 0; kc < 4; kc++)
      b[ct][kc] = sW8[(ct * 16 + l15) * 16 + kc * 4 + quad];

  int row = rbase + l15;
  row = row < n ? row : n - 1;
  const bf16x8* X8 = (const bf16x8*)Xb;
  bf16x8 a[4];
#pragma unroll
  for (int kc = 0; kc < 4; kc++)
    a[kc] = X8[(size_t)row * 16 + kc * 4 + quad];

  floatx4 acc[8];
#pragma unroll
  for (int ct = 0; ct < 8; ct++) acc[ct] = (floatx4){0.f, 0.f, 0.f, 0.f};

#pragma unroll
  for (int kc = 0; kc < 4; kc++)
#pragma unroll
    for (int ct = 0; ct < 8; ct++)
      acc[ct] = __builtin_amdgcn_mfma_f32_16x16x32_bf16(a[kc], b[ct][kc], acc[ct], 0, 0, 0);

  const int orow = rbase + quad * 4;
#pragma unroll
  for (int ct = 0; ct < 8; ct++) {
    const int c = ct * 16 + l15;
    const float bv = bias ? bias[c] : 0.f;
#pragma unroll
    for (int r4 = 0; r4 < 4; r4++) {
      int r = orow + r4;
      if (r < n) Y[(size_t)r * 128 + c] = f2bs(acc[ct][r4] + bv);
    }
  }
}

// ---------------- aggregation ----------------
// FOUR nodes per wave: 16-lane quarter-waves each own a node; lane covers
// 8 bf16 cols as one uint4 (16 B). CSR segments are 16-padded: the inner
// loop batches SIXTEEN edges — 8 int4 epk reads + 16 uint4 gathers issued
// before any consumption, doubling rows-in-flight vs the 8-edge version
// (latency-bound fix; pads gather cache-hot H[0] with weight 0).
static __device__ __forceinline__ void fma8(float wgt, uint4 h, float* a) {
  a[0] = fmaf(wgt, bf_lo(h.x), a[0]);
  a[1] = fmaf(wgt, bf_hi(h.x), a[1]);
  a[2] = fmaf(wgt, bf_lo(h.y), a[2]);
  a[3] = fmaf(wgt, bf_hi(h.y), a[3]);
  a[4] = fmaf(wgt, bf_lo(h.z), a[4]);
  a[5] = fmaf(wgt, bf_hi(h.z), a[5]);
  a[6] = fmaf(wgt, bf_lo(h.w), a[6]);
  a[7] = fmaf(wgt, bf_hi(h.w), a[7]);
}

__global__ __launch_bounds__(256, 4) void k_agg(
    const uint4* __restrict__ H,         // bf16x8 per lane [n*16]
    const int* __restrict__ rs,
    const int* __restrict__ bsum,
    const int* __restrict__ tot,
    const int2* __restrict__ epk,
    const float* __restrict__ dinv,
    const float* __restrict__ bias,
    const uint4* __restrict__ resid,     // bf16x8 or null
    uint4* __restrict__ outb,            // bf16 out (layers 0,1) or null
    float4* __restrict__ outf,           // f32 out (layer 2) or null
    int n) {
  int node = blockIdx.x * 16 + (threadIdx.x >> 4);
  int l = threadIdx.x & 15;
  if (node >= n) return;

  float di = dinv[node];
  float ws = di * di;
  uint4 hv = H[(size_t)node * 16 + l];
  float a[8];
  a[0] = bf_lo(hv.x) * ws; a[1] = bf_hi(hv.x) * ws;
  a[2] = bf_lo(hv.y) * ws; a[3] = bf_hi(hv.y) * ws;
  a[4] = bf_lo(hv.z) * ws; a[5] = bf_hi(hv.z) * ws;
  a[6] = bf_lo(hv.w) * ws; a[7] = bf_hi(hv.w) * ws;

  int beg = rs[node] + bsum[node >> 10];
  int pdeg = (tot[node] + 15) & ~15;   // 16-padded degree
  const int4* epk4 = (const int4*)epk;

  for (int j = 0; j < pdeg; j += 16) {
    int b2 = (beg + j) >> 1;           // int4 index (beg is 16-aligned)
    int4 e[8];
#pragma unroll
    for (int q = 0; q < 8; q++) e[q] = epk4[b2 + q];
    uint4 h[16];
#pragma unroll
    for (int q = 0; q < 8; q++) {
      h[2 * q]     = H[(size_t)(unsigned)e[q].x * 16 + l];
      h[2 * q + 1] = H[(size_t)(unsigned)e[q].z * 16 + l];
    }
#pragma unroll
    for (int q = 0; q < 8; q++) {
      fma8(__int_as_float(e[q].y), h[2 * q], a);
      fma8(__int_as_float(e[q].w), h[2 * q + 1], a);
    }
  }

  float4 bl = ((const float4*)bias)[l * 2];
  float4 bh = ((const float4*)bias)[l * 2 + 1];
  a[0] = fmaxf(a[0] + bl.x, 0.f); a[1] = fmaxf(a[1] + bl.y, 0.f);
  a[2] = fmaxf(a[2] + bl.z, 0.f); a[3] = fmaxf(a[3] + bl.w, 0.f);
  a[4] = fmaxf(a[4] + bh.x, 0.f); a[5] = fmaxf(a[5] + bh.y, 0.f);
  a[6] = fmaxf(a[6] + bh.z, 0.f); a[7] = fmaxf(a[7] + bh.w, 0.f);
  if (resid) {
    uint4 r = resid[(size_t)node * 16 + l];
    a[0] += bf_lo(r.x); a[1] += bf_hi(r.x);
    a[2] += bf_lo(r.y); a[3] += bf_hi(r.y);
    a[4] += bf_lo(r.z); a[5] += bf_hi(r.z);
    a[6] += bf_lo(r.w); a[7] += bf_hi(r.w);
  }
  if (outb) {
    uint4 o;
    o.x = pack2(a[0], a[1]); o.y = pack2(a[2], a[3]);
    o.z = pack2(a[4], a[5]); o.w = pack2(a[6], a[7]);
    outb[(size_t)node * 16 + l] = o;
  } else {
    float4 o0; o0.x = a[0]; o0.y = a[1]; o0.z = a[2]; o0.w = a[3];
    float4 o1; o1.x = a[4]; o1.y = a[5]; o1.z = a[6]; o1.w = a[7];
    outf[(size_t)node * 32 + l * 2] = o0;
    outf[(size_t)node * 32 + l * 2 + 1] = o1;
  }
}

extern "C" void kernel_launch(void* const* d_in, const int* in_sizes, int n_in,
                              void* d_out, int out_size, void* d_ws, size_t ws_size,
                              hipStream_t stream) {
  const float* x  = (const float*)d_in[0];
  const int* edges = (const int*)d_in[1];
  const float* W0 = (const float*)d_in[2];
  const float* b0 = (const float*)d_in[3];
  const float* W1 = (const float*)d_in[4];
  const float* b1 = (const float*)d_in[5];
  const float* W2 = (const float*)d_in[6];
  const float* b2 = (const float*)d_in[7];
  const float* Wr = (const float*)d_in[8];
  const float* br = (const float*)d_in[9];

  int N = in_sizes[0] / 128;
  int E = in_sizes[1] / 2;
  const int* src = edges;
  const int* dst = edges + E;

  char* ws = (char*)d_ws;
  size_t off = 0;
  auto alloc = [&](size_t bytes) -> void* {
    void* p = ws + off; off = WS_ALIGN(off + bytes); return p;
  };
  int*   tot    = (int*)  alloc((size_t)N * 4);     // true in-degree (pre-loop)
  float* dinv   = (float*)alloc((size_t)N * 4);
  int*   rs     = (int*)  alloc((size_t)(N + 1) * 4);
  int*   bsum   = (int*)  alloc(1024);
  int2*  epk    = (int2*) alloc(((size_t)E + 16 * (size_t)N) * 8); // 16-padded CSR
  unsigned short* xb = (unsigned short*)alloc((size_t)N * 128 * 2);
  unsigned short* Wt = (unsigned short*)alloc((size_t)4 * 16384 * 2);
  unsigned short* A  = (unsigned short*)alloc((size_t)N * 128 * 2);
  unsigned short* Hb = (unsigned short*)alloc((size_t)N * 128 * 2);
  unsigned short* R  = (unsigned short*)alloc((size_t)N * 128 * 2);
  int* pos = (int*)A;   // pos[E] only lives between k_count and k_fill;
                        // A is first written after k_fill completes.
  // 8 per-XCD count planes (stride NP, 64B-multiple so no line straddles two
  // planes). Alias into Hb: dead until the first k_agg writes Hb (post-fill).
  int NP = (N + 15) & ~15;
  int* cnt8 = (int*)Hb;
  int nz = 8 * NP;
  (void)ws_size; (void)n_in; (void)out_size;

  int nb1 = (N + 1023) / 1024;   // 98 for N=100000 (must be <= 128)

  // ---- fused prep + CSR build ----
  int n4 = N * 128 / 4;
  int zb = (nz + 255) / 256;
  int xbn = (n4 + 255) / 256;
  k_prep <<<zb + xbn + 256, 256, 0, stream>>>(x, (unsigned*)xb, n4, cnt8, nz,
                                              W0, W1, W2, Wr, Wt, zb, xbn);
  k_count<<<(E + 255) / 256, 256, 0, stream>>>(dst, E, cnt8, pos, NP);
  k_scan1<<<nb1, 1024, 0, stream>>>(cnt8, N, NP, rs, bsum, dinv, tot);
  k_scan2<<<1, 128, 0, stream>>>(bsum, nb1);
  k_fill <<<(E + N + 255) / 256, 256, 0, stream>>>(src, dst, E, rs, bsum, pos,
                                                   cnt8, tot, NP, dinv, epk, N);

  // ---- GCN layers ----
  int gb = (N + 63) / 64;
  int ab = (N + 15) / 16;   // 16 nodes (quarter-waves) per 256-thread block

  unsigned short* Wt0 = Wt;
  unsigned short* Wt1 = Wt + 16384;
  unsigned short* Wt2 = Wt + 2 * 16384;
  unsigned short* Wtr = Wt + 3 * 16384;

  k_gemm_mfma<<<gb, 256, 0, stream>>>(xb, Wtr, br, R, N);       // residual
  k_gemm_mfma<<<gb, 256, 0, stream>>>(xb, Wt0, nullptr, A, N);
  k_agg<<<ab, 256, 0, stream>>>((const uint4*)A, rs, bsum, tot, epk, dinv, b0,
                                (const uint4*)R, (uint4*)Hb, nullptr, N);
  k_gemm_mfma<<<gb, 256, 0, stream>>>(Hb, Wt1, nullptr, A, N);
  k_agg<<<ab, 256, 0, stream>>>((const uint4*)A, rs, bsum, tot, epk, dinv, b1,
                                nullptr, (uint4*)R, nullptr, N);
  k_gemm_mfma<<<gb, 256, 0, stream>>>(R, Wt2, nullptr, A, N);
  k_agg<<<ab, 256, 0, stream>>>((const uint4*)A, rs, bsum, tot, epk, dinv, b2,
                                nullptr, nullptr, (float4*)d_out, N);
}

// Round 6
// 515.023 us; speedup vs baseline: 1.0238x; 1.0231x over previous
//
#include <hip/hip_runtime.h>
#include <hip/hip_bf16.h>
#include <cstdint>

// ---------------------------------------------------------------------------
// 3-layer GCN on MI355X — bf16 feature pipeline, f32 accumulate.
//   k_prep : x->bf16 | W->Wt bf16 | zero cnt, A zero-row, ovfn
//   k_gemm : R = bf16(xb@Wr + br)                      (residual)
//   k_fill1p: ONE atomic pass -> fixed-stride CSR: rank=atomicAdd(cnt[d]);
//             rank<32 -> epk[d*32+rank]=src, else tiny overflow list.
//   k_aux  : dinv=rsqrt(cnt+1); pad epk slots [min(c,32), ceil8) with N.
//   A  = bf16( dinv * (xb @ W0) )    (dinv folded into GEMM epilogue)
//   H0 = bf16( relu(dinv_d * (A[self] + sum_src A[src]) + b0) + R )
//   ... layers 1,2 same; layer 2 writes f32 to d_out.
//
// History: R10-12 — k_count atomics are memory-side regardless of scope
// (replica planes no-op); k_agg pinned at ~3.8 TB/s with FETCH == 8 XCD x
// 25.6 MB (each XCD pulls H once; L2 captures all reuse) -> near structural
// floor. R13/R14 (fused k_fc: GEMM blocks + atomic blocks in one dispatch)
// died twice with container-level failures; only unproven component was the
// divergent fused dispatch. R15 (this): DE-FUSED pipeline — every kernel is
// a small delta from hardware-proven code: k_fill1p = R12's k_count + one
// store; k_gemm = proven GEMM + epilogue dinv multiply; one-pass CSR keeps
// the R13 win (count+scan1+scan2+fill -> fill1p+aux, 13 -> 10 launches,
// epk 8B->4B per edge).
// ---------------------------------------------------------------------------

#define WS_ALIGN(x) (((x) + 255) & ~(size_t)255)

typedef __bf16 bf16x8 __attribute__((ext_vector_type(8)));
typedef float  floatx4 __attribute__((ext_vector_type(4)));

static __device__ __forceinline__ float bf_lo(unsigned u) {
  return __builtin_bit_cast(float, u << 16);
}
static __device__ __forceinline__ float bf_hi(unsigned u) {
  return __builtin_bit_cast(float, u & 0xffff0000u);
}
// f32 -> bf16 round-to-nearest-even (finite inputs only)
static __device__ __forceinline__ unsigned short f2bs(float f) {
  unsigned u = __builtin_bit_cast(unsigned, f);
  return (unsigned short)((u + 0x7fffu + ((u >> 16) & 1u)) >> 16);
}
static __device__ __forceinline__ unsigned pack2(float a, float b) {
  return (unsigned)f2bs(a) | ((unsigned)f2bs(b) << 16);
}

// ------- prep: zero cnt | x->bf16 | W->Wt bf16 | zero A row N | ovfn=0 -----
__global__ void k_prep(const float* __restrict__ x, unsigned* __restrict__ xb, int n4,
                       int* __restrict__ cnt, int n,
                       const float* __restrict__ W0, const float* __restrict__ W1,
                       const float* __restrict__ W2, const float* __restrict__ Wr,
                       unsigned short* __restrict__ Wt,
                       unsigned short* __restrict__ A, int* __restrict__ ovfn,
                       int zb, int xbn) {
  int b = blockIdx.x;
  if (b < zb) {
    int i = b * 256 + threadIdx.x;
    if (i < n) cnt[i] = 0;
  } else if (b < zb + xbn) {
    int i = (b - zb) * 256 + threadIdx.x;
    if (i < n4) {
      float4 v = ((const float4*)x)[i];
      uint2 o;
      o.x = pack2(v.x, v.y);
      o.y = pack2(v.z, v.w);
      ((uint2*)xb)[i] = o;
    }
  } else {
    int wb = b - zb - xbn;            // 0..256
    if (wb < 256) {
      int mat = wb >> 6, blk = wb & 63;
      const float* W = mat == 0 ? W0 : mat == 1 ? W1 : mat == 2 ? W2 : Wr;
      unsigned short* T = Wt + (size_t)mat * 16384;
      int i = blk * 256 + threadIdx.x;  // i = k*128 + nn, coalesced read
      int k = i >> 7, nn = i & 127;
      T[nn * 128 + k] = f2bs(W[i]);
    } else {
      // zero row N of A (pad-gather target) + overflow counter
      if (threadIdx.x < 16) {
        uint4 z; z.x = 0; z.y = 0; z.z = 0; z.w = 0;
        ((uint4*)(A + (size_t)n * 128))[threadIdx.x] = z;
      }
      if (threadIdx.x == 16) *ovfn = 0;
    }
  }
}

// ---------------- bf16 MFMA GEMM: Y = bf16( dv[r] * (Xb@W) + bias ) --------
// Wt pre-transposed [n][k] bf16, staged in 32 KB LDS. Block = 256 thr =
// 4 waves; each wave computes a 16-row x 128-col strip with 32 MFMAs.
// Layouts (verified, learn_hip m89/m120): A[m=lane&15][k=quad*8+j],
// B[k=quad*8+j][n=lane&15], C/D col=lane&15 row=quad*4+reg.
__global__ __launch_bounds__(256, 2) void k_gemm_mfma(
    const unsigned short* __restrict__ Xb,
    const unsigned short* __restrict__ Wt,
    const float* __restrict__ bias,
    const float* __restrict__ dv,
    unsigned short* __restrict__ Y,
    int n) {
  __shared__ unsigned short sWt[128 * 128];
  {
    const uint4* s4 = (const uint4*)Wt;
    uint4* d4 = (uint4*)sWt;
    for (int i = threadIdx.x; i < 2048; i += 256) d4[i] = s4[i];
  }
  __syncthreads();

  const int lane = threadIdx.x & 63;
  const int wave = threadIdx.x >> 6;
  const int l15 = lane & 15;
  const int quad = lane >> 4;
  const int rbase = blockIdx.x * 64 + wave * 16;

  const bf16x8* sW8 = (const bf16x8*)sWt;
  bf16x8 b[8][4];
#pragma unroll
  for (int ct = 0; ct < 8; ct++)
#pragma unroll
    for (int kc = 0; kc < 4; kc++)
      b[ct][kc] = sW8[(ct * 16 + l15) * 16 + kc * 4 + quad];

  int row = rbase + l15;
  row = row < n ? row : n - 1;
  const bf16x8* X8 = (const bf16x8*)Xb;
  bf16x8 a[4];
#pragma unroll
  for (int kc = 0; kc < 4; kc++)
    a[kc] = X8[(size_t)row * 16 + kc * 4 + quad];

  floatx4 acc[8];
#pragma unroll
  for (int ct = 0; ct < 8; ct++) acc[ct] = (floatx4){0.f, 0.f, 0.f, 0.f};

#pragma unroll
  for (int kc = 0; kc < 4; kc++)
#pragma unroll
    for (int ct = 0; ct < 8; ct++)
      acc[ct] = __builtin_amdgcn_mfma_f32_16x16x32_bf16(a[kc], b[ct][kc], acc[ct], 0, 0, 0);

  const int orow = rbase + quad * 4;
  float4 dvv;
  dvv.x = 1.f; dvv.y = 1.f; dvv.z = 1.f; dvv.w = 1.f;
  if (dv) {
    int od = orow < n ? orow : 0;      // orow is 4-aligned, n % 4 == 0
    dvv = *(const float4*)(dv + od);
  }
#pragma unroll
  for (int ct = 0; ct < 8; ct++) {
    const int c = ct * 16 + l15;
    const float bv = bias ? bias[c] : 0.f;
#pragma unroll
    for (int r4 = 0; r4 < 4; r4++) {
      int r = orow + r4;
      float dm = r4 == 0 ? dvv.x : r4 == 1 ? dvv.y : r4 == 2 ? dvv.z : dvv.w;
      if (r < n) Y[(size_t)r * 128 + c] = f2bs(acc[ct][r4] * dm + bv);
    }
  }
}

// --------- one-pass CSR fill (== R12's k_count + one conditional store) ----
__global__ void k_fill1p(const int* __restrict__ srcv, const int* __restrict__ dstv,
                         int E, int* __restrict__ cnt, int* __restrict__ epk,
                         int2* __restrict__ ovf, int* __restrict__ ovfn) {
  int e = blockIdx.x * blockDim.x + threadIdx.x;
  if (e < E) {
    int s = srcv[e], d = dstv[e];
    int rank = atomicAdd(&cnt[d], 1);
    if (rank < 32) {
      epk[(size_t)d * 32 + rank] = s;
    } else {
      int o = atomicAdd(ovfn, 1);
      if (o < E) {                     // defensive clamp (can't exceed)
        int2 t; t.x = s; t.y = d;
        ovf[o] = t;
      }
    }
  }
}

// --------- aux: dinv from degree; pad epk slots with zero-row index --------
__global__ void k_aux(const int* __restrict__ cnt, float* __restrict__ dinv,
                      int* __restrict__ epk, int n) {
  int i = blockIdx.x * 256 + threadIdx.x;
  if (i < n) {
    int c = cnt[i];
    dinv[i] = rsqrtf((float)(c + 1));   // +1 = self-loop; always > 0
    int cm = c < 32 ? c : 32;
    int cp = (cm + 7) & ~7;
    for (int k = cm; k < cp; k++) epk[(size_t)i * 32 + k] = n;  // zero row
  }
}

// ---------------- aggregation ----------------
// FOUR nodes per wave: 16-lane quarter-waves each own a node; lane covers
// 8 bf16 cols as one uint4 (16 B). epk entries are 4 B src indices into the
// PRE-SCALED A (A[s] = dinv[s] * h[s]); no per-edge weight. Fixed stride 32,
// 8-padded with zero-row N. Nodes with degree > 32 additionally walk the
// (tiny) overflow list. NOTE: all k_agg calls gather from A (N+1 rows).
static __device__ __forceinline__ void add8(uint4 h, float* a) {
  a[0] += bf_lo(h.x); a[1] += bf_hi(h.x);
  a[2] += bf_lo(h.y); a[3] += bf_hi(h.y);
  a[4] += bf_lo(h.z); a[5] += bf_hi(h.z);
  a[6] += bf_lo(h.w); a[7] += bf_hi(h.w);
}

__global__ __launch_bounds__(256, 4) void k_agg(
    const uint4* __restrict__ H,         // bf16x8 per lane [(n+1)*16], prescaled
    const int* __restrict__ cnt,
    const int* __restrict__ epk,
    const float* __restrict__ dinv,
    const float* __restrict__ bias,
    const uint4* __restrict__ resid,     // bf16x8 or null
    uint4* __restrict__ outb,            // bf16 out (layers 0,1) or null
    float4* __restrict__ outf,           // f32 out (layer 2) or null
    const int2* __restrict__ ovf, const int* __restrict__ ovfn,
    int n, int Ecap) {
  int node = blockIdx.x * 16 + (threadIdx.x >> 4);
  int l = threadIdx.x & 15;
  if (node >= n) return;

  int tot = cnt[node];
  int cm = tot < 32 ? tot : 32;
  int pdeg = (cm + 7) & ~7;

  uint4 hv = H[(size_t)node * 16 + l];   // self term (prescaled)
  float a[8];
  a[0] = bf_lo(hv.x); a[1] = bf_hi(hv.x);
  a[2] = bf_lo(hv.y); a[3] = bf_hi(hv.y);
  a[4] = bf_lo(hv.z); a[5] = bf_hi(hv.z);
  a[6] = bf_lo(hv.w); a[7] = bf_hi(hv.w);

  const int4* epk4 = (const int4*)(epk + (size_t)node * 32);
  for (int j = 0; j < pdeg; j += 8) {
    int4 e0 = epk4[j >> 2];
    int4 e1 = epk4[(j >> 2) + 1];
    uint4 h0 = H[(size_t)(unsigned)e0.x * 16 + l];
    uint4 h1 = H[(size_t)(unsigned)e0.y * 16 + l];
    uint4 h2 = H[(size_t)(unsigned)e0.z * 16 + l];
    uint4 h3 = H[(size_t)(unsigned)e0.w * 16 + l];
    uint4 h4 = H[(size_t)(unsigned)e1.x * 16 + l];
    uint4 h5 = H[(size_t)(unsigned)e1.y * 16 + l];
    uint4 h6 = H[(size_t)(unsigned)e1.z * 16 + l];
    uint4 h7 = H[(size_t)(unsigned)e1.w * 16 + l];
    add8(h0, a); add8(h1, a); add8(h2, a); add8(h3, a);
    add8(h4, a); add8(h5, a); add8(h6, a); add8(h7, a);
  }
  if (tot > 32) {                        // rare: walk overflow list
    int no = *ovfn;
    no = no < Ecap ? no : Ecap;          // defensive clamp
    for (int i = 0; i < no; i++) {
      int2 t = ovf[i];
      if (t.y == node) add8(H[(size_t)(unsigned)t.x * 16 + l], a);
    }
  }

  float dn = dinv[node];
  float4 bl = ((const float4*)bias)[l * 2];
  float4 bh = ((const float4*)bias)[l * 2 + 1];
  a[0] = fmaxf(fmaf(a[0], dn, bl.x), 0.f); a[1] = fmaxf(fmaf(a[1], dn, bl.y), 0.f);
  a[2] = fmaxf(fmaf(a[2], dn, bl.z), 0.f); a[3] = fmaxf(fmaf(a[3], dn, bl.w), 0.f);
  a[4] = fmaxf(fmaf(a[4], dn, bh.x), 0.f); a[5] = fmaxf(fmaf(a[5], dn, bh.y), 0.f);
  a[6] = fmaxf(fmaf(a[6], dn, bh.z), 0.f); a[7] = fmaxf(fmaf(a[7], dn, bh.w), 0.f);
  if (resid) {
    uint4 r = resid[(size_t)node * 16 + l];
    a[0] += bf_lo(r.x); a[1] += bf_hi(r.x);
    a[2] += bf_lo(r.y); a[3] += bf_hi(r.y);
    a[4] += bf_lo(r.z); a[5] += bf_hi(r.z);
    a[6] += bf_lo(r.w); a[7] += bf_hi(r.w);
  }
  if (outb) {
    uint4 o;
    o.x = pack2(a[0], a[1]); o.y = pack2(a[2], a[3]);
    o.z = pack2(a[4], a[5]); o.w = pack2(a[6], a[7]);
    outb[(size_t)node * 16 + l] = o;
  } else {
    float4 o0; o0.x = a[0]; o0.y = a[1]; o0.z = a[2]; o0.w = a[3];
    float4 o1; o1.x = a[4]; o1.y = a[5]; o1.z = a[6]; o1.w = a[7];
    outf[(size_t)node * 32 + l * 2] = o0;
    outf[(size_t)node * 32 + l * 2 + 1] = o1;
  }
}

extern "C" void kernel_launch(void* const* d_in, const int* in_sizes, int n_in,
                              void* d_out, int out_size, void* d_ws, size_t ws_size,
                              hipStream_t stream) {
  const float* x  = (const float*)d_in[0];
  const int* edges = (const int*)d_in[1];
  const float* W0 = (const float*)d_in[2];
  const float* b0 = (const float*)d_in[3];
  const float* W1 = (const float*)d_in[4];
  const float* b1 = (const float*)d_in[5];
  const float* W2 = (const float*)d_in[6];
  const float* b2 = (const float*)d_in[7];
  const float* Wr = (const float*)d_in[8];
  const float* br = (const float*)d_in[9];

  int N = in_sizes[0] / 128;
  int E = in_sizes[1] / 2;
  const int* src = edges;
  const int* dst = edges + E;

  char* ws = (char*)d_ws;
  size_t off = 0;
  auto alloc = [&](size_t bytes) -> void* {
    void* p = ws + off; off = WS_ALIGN(off + bytes); return p;
  };
  int*   cnt  = (int*)  alloc((size_t)N * 4);
  float* dinv = (float*)alloc((size_t)N * 4);
  int*   ovfn = (int*)  alloc(256);
  int2*  ovf  = (int2*) alloc((size_t)E * 8);
  int*   epk  = (int*)  alloc((size_t)N * 32 * 4);           // fixed-stride CSR
  unsigned short* xb = (unsigned short*)alloc((size_t)N * 128 * 2);
  unsigned short* Wt = (unsigned short*)alloc((size_t)4 * 16384 * 2);
  unsigned short* A  = (unsigned short*)alloc(((size_t)N + 1) * 128 * 2); // +zero row
  unsigned short* Hb = (unsigned short*)alloc((size_t)N * 128 * 2);
  unsigned short* R  = (unsigned short*)alloc((size_t)N * 128 * 2);
  (void)ws_size; (void)n_in; (void)out_size;

  // ---- prep ----
  int n4 = N * 128 / 4;
  int zb = (N + 255) / 256;
  int xbn = (n4 + 255) / 256;
  k_prep<<<zb + xbn + 257, 256, 0, stream>>>(x, (unsigned*)xb, n4, cnt, N,
                                             W0, W1, W2, Wr, Wt, A, ovfn, zb, xbn);

  // ---- CSR build (one atomic pass) + residual GEMM ----
  int gb = (N + 63) / 64;
  int eb = (E + 255) / 256;
  unsigned short* Wt0 = Wt;
  unsigned short* Wt1 = Wt + 16384;
  unsigned short* Wt2 = Wt + 2 * 16384;
  unsigned short* Wtr = Wt + 3 * 16384;
  k_fill1p<<<eb, 256, 0, stream>>>(src, dst, E, cnt, epk, ovf, ovfn);
  k_gemm_mfma<<<gb, 256, 0, stream>>>(xb, Wtr, br, nullptr, R, N);   // residual
  k_aux<<<(N + 255) / 256, 256, 0, stream>>>(cnt, dinv, epk, N);

  // ---- GCN layers (GEMMs prescale rows by dinv) ----
  int ab = (N + 15) / 16;   // 16 nodes (quarter-waves) per 256-thread block

  k_gemm_mfma<<<gb, 256, 0, stream>>>(xb, Wt0, nullptr, dinv, A, N);
  k_agg<<<ab, 256, 0, stream>>>((const uint4*)A, cnt, epk, dinv, b0,
                                (const uint4*)R, (uint4*)Hb, nullptr, ovf, ovfn, N, E);
  k_gemm_mfma<<<gb, 256, 0, stream>>>(Hb, Wt1, nullptr, dinv, A, N);
  k_agg<<<ab, 256, 0, stream>>>((const uint4*)A, cnt, epk, dinv, b1,
                                nullptr, (uint4*)R, nullptr, ovf, ovfn, N, E);
  k_gemm_mfma<<<gb, 256, 0, stream>>>(R, Wt2, nullptr, dinv, A, N);
  k_agg<<<ab, 256, 0, stream>>>((const uint4*)A, cnt, epk, dinv, b2,
                                nullptr, nullptr, (float4*)d_out, ovf, ovfn, N, E);
}